// Round 5
// baseline (285.099 us; speedup 1.0000x reference)
//
#include <hip/hip_runtime.h>

#define SQRT5F 2.2360679774997896f

// out[i,a,j,b] = c^2 * ( (a==b) * A(i,j) * inv_l2[a]  -  5*fr(i,j)*D[i,j,a]*D[i,j,b] )
// with D[i,j,k] = (X1[i,k]-X2[j,k]) * inv_l2[k]
//      r^2      = sum_k (X1[i,k]-X2[j,k])^2 * inv_l2[k]
//      fr       = (5/3) * exp(-sqrt5 * r)
//      A        = fr * (1 + sqrt5 * r)
//
// v6: COMPACT MARCHING WRITE FRONT (fill's actual pattern).
// Evidence ladder: fill = 6.5 TB/s at ~10% occupancy -> small grid-stride
// grid whose resident waves write a ~1-2MB contiguous window that marches.
// v1/v3 (2048 blocks scattered over 256MB) = 2.9 TB/s; v4 (8192 scattered
// per-wave streams) = 2.4; v5 (contiguous per block but 64MB resident
// front) = 2.55. Model: write BW = inflight-bytes / write-latency; a
// compact front keeps 1-2 DRAM rows open per channel (row hits, low
// latency); scattered fronts juggle 100s of rows (row misses, 2-3x
// latency -> BW halves). v6: output = 65536 chunks of 4KB in address
// order; 1024 persistent blocks (4/CU) grid-stride the chunk list ->
// resident front = 4MB contiguous, marching. Since gridDim is a multiple
// of chunks-per-i (64), jb and a are BLOCK-INVARIANT -> X2 row, a-selectors,
// diag mask all hoisted (v3's hoisting); only the X1 row (32B, L1-hot)
// changes per iteration. ~55 VALU per 4KB chunk per wave = 28% VALU issue
// at 16 waves/CU -> BW-dominated if the front theory holds.

__global__ __launch_bounds__(256) void deriv2_matern52_kernel(
    const float* __restrict__ X1,
    const float* __restrict__ X2,
    const float* __restrict__ c_ptr,
    const float* __restrict__ l_ptr,
    float* __restrict__ out,
    int m /* = 1024, multiple of 128 */,
    int n /* = 1024 */)
{
    const int t = threadIdx.x;
    const int h = t & 1;            // which half of the 8-float b-run
    const int p = t >> 1;           // j-offset within the 128-j chunk

    const int bid = blockIdx.x;
    const int G   = gridDim.x;      // multiple of 8*jbn -> jb, a invariant

    const int jbn   = m >> 7;       // j-chunks per (i,a)
    const int jb    = bid % jbn;                 // invariant along q-walk
    const int a     = (bid / jbn) & 7;           // invariant
    const int i0    = bid / (jbn * 8);
    const int istep = G / (jbn * 8);

    const int j = (jb << 7) + p;

    const float c  = c_ptr[0];
    const float c2 = c * c;

    // lengthscales -> 1/l^2 (block-uniform, loop-invariant)
    float inv_l2[8];
#pragma unroll
    for (int k = 0; k < 8; ++k) {
        const float lv = l_ptr[k];
        inv_l2[k] = 1.0f / (lv * lv);
    }

    // selectors for block-uniform runtime 'a' (no runtime reg indexing)
    float asel[8];
#pragma unroll
    for (int k = 0; k < 8; ++k) asel[k] = (k == a) ? 1.0f : 0.0f;

    float il_a = 0.0f;              // inv_l2[a]
#pragma unroll
    for (int k = 0; k < 8; ++k) il_a = fmaf(asel[k], inv_l2[k], il_a);

    // diagonal hits this lane's quad iff (a>>2)==h, at element (a&3)
    float dk[4];
#pragma unroll
    for (int k = 0; k < 4; ++k)
        dk[k] = (((a & 3) == k) && ((a >> 2) == h)) ? 1.0f : 0.0f;

    // X2 row: loop-invariant (j fixed for this block)
    const float4 x2a = ((const float4*)(X2 + (size_t)j * 8))[0];
    const float4 x2b = ((const float4*)(X2 + (size_t)j * 8))[1];
    const float x2v[8] = { x2a.x, x2a.y, x2a.z, x2a.w,
                           x2b.x, x2b.y, x2b.z, x2b.w };

    const float c2il = c2 * il_a;   // diag scale (loop-invariant)
    const float m5c2 = -5.0f * c2;  // pair scale (loop-invariant)

    // chunk (i,a,jb) base + this thread's 16B slot (t*4 floats = p*8+h*4)
    float* op = out + ((size_t)(i0 * 8 + a) * (size_t)m + (size_t)(jb << 7)) * 8
                    + (size_t)t * 4;
    const size_t ostep = (size_t)istep * 8 * (size_t)m * 8;  // i += istep

    for (int i = i0; i < n; i += istep, op += ostep) {
        // X1 row (32B wave-uniform broadcast; X1 = 32KB total -> cache-hot)
        const float4 x1a = ((const float4*)(X1 + (size_t)i * 8))[0];
        const float4 x1b = ((const float4*)(X1 + (size_t)i * 8))[1];
        const float x1v[8] = { x1a.x, x1a.y, x1a.z, x1a.w,
                               x1b.x, x1b.y, x1b.z, x1b.w };

        float D[8];
        float r2 = 0.0f;
#pragma unroll
        for (int k = 0; k < 8; ++k) {
            const float dx = x1v[k] - x2v[k];
            D[k] = dx * inv_l2[k];
            r2 += dx * D[k];                 // dx^2 * inv_l2
        }

        const float r    = sqrtf(r2);
        const float fr   = (5.0f / 3.0f) * expf(-SQRT5F * r);
        const float Acil = fr * (1.0f + SQRT5F * r) * c2il;  // diag value
        const float cf   = m5c2 * fr;                        // pair coeff

        // D[a] via selector reduction (a block-uniform)
        float Da = 0.0f;
#pragma unroll
        for (int k = 0; k < 8; ++k) Da = fmaf(asel[k], D[k], Da);
        const float Dca = cf * Da;

        float v[4];
#pragma unroll
        for (int k = 0; k < 4; ++k) {
            const float Db = h ? D[4 + k] : D[k];   // cndmask, no memory
            v[k] = fmaf(dk[k], Acil, Dca * Db);
        }

        // lane t -> byte offset t*16 in the 4KB chunk: dense 1KiB/wave-instr;
        // resident blocks cover a contiguous 4MB window marching through out.
        *(float4*)op = make_float4(v[0], v[1], v[2], v[3]);
    }
}

extern "C" void kernel_launch(void* const* d_in, const int* in_sizes, int n_in,
                              void* d_out, int out_size, void* d_ws, size_t ws_size,
                              hipStream_t stream) {
    const float* X1 = (const float*)d_in[0];
    const float* X2 = (const float*)d_in[1];
    const float* c  = (const float*)d_in[2];
    const float* l  = (const float*)d_in[3];
    float* out = (float*)d_out;

    const int d = in_sizes[3];        // 8
    const int n = in_sizes[0] / d;    // 1024
    const int m = in_sizes[1] / d;    // 1024

    const int jbn = m >> 7;           // 8 j-chunks per (i,a)
    // Persistent grid: multiple of 8*jbn (so jb,a are block-invariant),
    // sized for 4 blocks/CU -> 16 waves/CU, 4MB resident write front.
    int G = jbn * 8 * 16;             // = 1024 for m = 1024 (istep = 16)
    if (G / (jbn * 8) > n) G = jbn * 8 * n;   // degenerate small-n guard
    dim3 grid(G);
    dim3 block(256);
    deriv2_matern52_kernel<<<grid, block, 0, stream>>>(X1, X2, c, l, out, m, n);
}

// Round 6
// 256.746 us; speedup vs baseline: 1.1104x; 1.1104x over previous
//
#include <hip/hip_runtime.h>

#define SQRT5F 2.2360679774997896f

// out[i,a,j,b] = c^2 * ( (a==b) * A(i,j) * inv_l2[a]  -  5*fr(i,j)*D[i,j,a]*D[i,j,b] )
// with D[i,j,k] = (X1[i,k]-X2[j,k]) * inv_l2[k]
//      r^2      = sum_k (X1[i,k]-X2[j,k])^2 * inv_l2[k]
//      fr       = (5/3) * exp(-sqrt5 * r)
//      A        = fr * (1 + sqrt5 * r)
//
// v7: v3's persistent structure, QUARTER THE GRID (512 blocks = 2/CU).
// Evidence ladder (kernel-portion): v1/v3 (2048 blks, 32 waves/CU,
// 8x4KB-strided chunks) ~92-95us = 2.9 TB/s; v4 scattered streams 113;
// v5 contiguous blocks 108; v6 compact marching front 125. ALL address-
// organization theories falsified. The single untested discriminator vs
// fillBufferAligned (6.5 TB/s): fill runs at ~10% OCCUPANCY (~3 waves/CU,
// ~800 concurrent write streams device-wide); all our variants ran 16-32
// waves/CU (4K-16K streams). Theory: concurrent-stream count per HBM
// pseudo-channel sets row-conflict rate -> write latency -> BW, which is
// why address reshuffling at constant concurrency never moved anything.
// v7 = v3 mapping (j/a/X2/selectors block-invariant, X1 L1-hot per iter)
// with grid 2048 -> 512: exactly 2 blocks/CU (perfect balance: each CU
// writes 16 iters x 2 x 32KB = 1.0MB), 8 waves/CU, ~4K streams.
// VALU check per SIMD: 2 waves x ~140cy per 8KB vs ~1550cy BW fair-share
// -> 18% issue, BW-dominated. If neutral: revert to v1, ROOFLINE.

__global__ __launch_bounds__(256) void deriv2_matern52_kernel(
    const float* __restrict__ X1,
    const float* __restrict__ X2,
    const float* __restrict__ c_ptr,
    const float* __restrict__ l_ptr,
    float* __restrict__ out,
    int m /* = 1024 */,
    int n /* = 1024 */,
    int jblocks /* = m>>7 */)
{
    const int t = threadIdx.x;
    const int h  = t & 1;                       // half of the 8-float b-run
    const int b0 = h << 2;                      // 0 or 4

    const int bid = blockIdx.x;
    const int jb  = bid % jblocks;              // invariant: gridDim.x % jblocks == 0
    const int i0  = bid / jblocks;
    const int istep = gridDim.x / jblocks;      // i advance per iteration
    const int j   = (jb << 7) + (t >> 1);

    const float c  = c_ptr[0];
    const float c2 = c * c;

    // lengthscales -> 1/l^2 (loop-invariant)
    float inv_l2[8];
#pragma unroll
    for (int k = 0; k < 8; ++k) {
        const float lv = l_ptr[k];
        inv_l2[k] = 1.0f / (lv * lv);
    }

    // X2 row (loop-invariant: j fixed for this block across all iterations)
    const float4 x2a = ((const float4*)(X2 + (size_t)j * 8))[0];
    const float4 x2b = ((const float4*)(X2 + (size_t)j * 8))[1];
    const float x2v[8] = { x2a.x, x2a.y, x2a.z, x2a.w,
                           x2b.x, x2b.y, x2b.z, x2b.w };

    const size_t astride = (size_t)m * 8;            // stride between consecutive a
    const size_t istride = (size_t)istep * 64 * m;   // out-advance per iteration
    float* op = out + (size_t)i0 * (size_t)(8 * m * 8) + (size_t)j * 8 + b0;

    for (int i = i0; i < n; i += istep, op += istride) {
        // X1 row (32B, wave-uniform broadcast; X1 is 32 KB total -> cache-hot)
        const float4 x1a = ((const float4*)(X1 + (size_t)i * 8))[0];
        const float4 x1b = ((const float4*)(X1 + (size_t)i * 8))[1];
        const float x1v[8] = { x1a.x, x1a.y, x1a.z, x1a.w,
                               x1b.x, x1b.y, x1b.z, x1b.w };

        float D[8];
        float r2 = 0.0f;
#pragma unroll
        for (int k = 0; k < 8; ++k) {
            const float dx = x1v[k] - x2v[k];
            D[k] = dx * inv_l2[k];
            r2 += dx * D[k];                     // dx^2 * inv_l2
        }

        const float r  = sqrtf(r2);
        const float fr = (5.0f / 3.0f) * expf(-SQRT5F * r);
        const float A  = fr * (1.0f + SQRT5F * r);

        const float Ac = A * c2;                 // diagonal coefficient
        const float cf = -5.0f * fr * c2;        // pair coefficient

        // this thread's 4 b-values (h-select -> cndmask, no memory)
        const float Db[4] = { D[b0 + 0], D[b0 + 1], D[b0 + 2], D[b0 + 3] };

#pragma unroll
        for (int a = 0; a < 8; ++a) {
            const float Dca = cf * D[a];
            float v[4];
#pragma unroll
            for (int k = 0; k < 4; ++k) v[k] = Dca * Db[k];
            // diagonal term lands in this thread's half iff h == a>>2,
            // at element a&3 (compile-time under the unroll)
            const float dsel = (h == (a >> 2)) ? 1.0f : 0.0f;
            v[a & 3] += dsel * (Ac * inv_l2[a]);

            *(float4*)(op + (size_t)a * astride) = make_float4(v[0], v[1], v[2], v[3]);
        }
    }
}

extern "C" void kernel_launch(void* const* d_in, const int* in_sizes, int n_in,
                              void* d_out, int out_size, void* d_ws, size_t ws_size,
                              hipStream_t stream) {
    const float* X1 = (const float*)d_in[0];
    const float* X2 = (const float*)d_in[1];
    const float* c  = (const float*)d_in[2];
    const float* l  = (const float*)d_in[3];
    float* out = (float*)d_out;

    const int d = in_sizes[3];        // 8
    const int n = in_sizes[0] / d;    // 1024
    const int m = in_sizes[1] / d;    // 1024

    const int jblocks = m >> 7;       // 128 pairs (256 threads) per j-block
    // Persistent grid: 512 blocks = exactly 2 blocks/CU (8 waves/CU, 25%
    // occupancy), multiple of jblocks so each block's j-range is invariant.
    // Perfect balance: every CU writes 2 x 16 iters x 32KB = 1.0 MB.
    int iper = 512 / jblocks;         // i-values per grid sweep (64 for m=1024)
    if (iper < 1) iper = 1;
    if (iper > n) iper = n;
    dim3 grid(jblocks * iper);
    dim3 block(256);
    deriv2_matern52_kernel<<<grid, block, 0, stream>>>(X1, X2, c, l, out, m, n, jblocks);
}